// Round 9
// baseline (797.004 us; speedup 1.0000x reference)
//
#include <hip/hip_runtime.h>
#include <cstddef>
#include <cstdint>

// Shapes fixed by reference setup_inputs():
#define T_LEN 2048
#define B_SZ  32
#define D_SZ  512
#define BD    (B_SZ * D_SZ)   // 16384

// ---------------------------------------------------------------------------
// GEMM — EXACT R5/R6 kernel (best measured: 464-470 us, VGPR 80, VALUBusy
// 84%, occupancy 30%). Five structural variants have lost to this body:
//   R2 reg-dbuf (733, VGPR 180), R3 full-swizzle glds (752, VGPR 180),
//   R4 hybrid ds_write B (543, conflicts up), R7 named-A read-once (516,
//   VGPR 92), R8 3-buf counted-vmcnt (500, VGPR 108, LDS 48K).
// Do not restructure without disasm-level evidence.
// Per output element: single sequential fmaf chain over k=0..511 ascending
// (k0 asc, kq asc, x/y/z/w asc), then + bias[e]. Bit-exact vs ref.
//  - A and B staged via global_load_lds into linear [2][128*16] tiles (32 KB).
//  - XOR quad swizzles, inverse-swizzled global source (rule #21):
//    A: p=q^(row&3); B: p=q^((row>>1)&3). Read offsets loop-invariant.
//  - ONE __syncthreads per 16-wide K-chunk; next chunk's glds issued before
//    compute, drained by the barrier.
//  - Bijective XCD swizzle (FETCH 272->85 MB proven).
// NOTE: SQ_LDS_BANK_CONFLICT ~3.3e7 is a glds wide-write artifact.
// NOTE: plain __launch_bounds__(256); (256,4) spilled acc (8.5x). Keep.
// ---------------------------------------------------------------------------
#define BM   128
#define BN   128

typedef const __attribute__((address_space(1))) uint32_t* gas1_t;
typedef __attribute__((address_space(3))) uint32_t* las3_t;

__global__ __launch_bounds__(256) void gemm8x8_kernel(
    const float* __restrict__ A,     // [rows, 512]
    const float* __restrict__ W,     // [512, 512]
    const float* __restrict__ bias,  // [512]
    float* __restrict__ Y)           // [rows, 512]
{
#pragma clang fp contract(off)
  __shared__ float As[2][BM * 16];     // 8 KB per buf, linear, glds dest
  __shared__ float Bs[2][BN * 16];     // 8 KB per buf, linear, glds dest

  const int tid = threadIdx.x;
  const int tx  = tid & 15;          // n-lane: n = tx + 16*j
  const int ty  = tid >> 4;          // m-lane: m = ty + 16*i (0..15)
  const int cA  = ty & 3;            // A read-side quad XOR
  const int cB  = (tx >> 1) & 3;     // B read-side quad XOR

  // Bijective XCD swizzle (n-fast).
  const int nwg  = (int)(gridDim.x * gridDim.y);
  const int orig = (int)(blockIdx.y * gridDim.x + blockIdx.x);
  const int q    = nwg >> 3, r = nwg & 7;
  const int xcd  = orig & 7, loc = orig >> 3;
  const int tix  = (xcd < r ? xcd * (q + 1) : r * (q + 1) + (xcd - r) * q) + loc;
  const int m0   = (tix >> 2) * BM;   // gridDim.y == 4 (D_SZ/BN)
  const int n0   = (tix & 3) * BN;

  // glds staging: wave w stages A segs {2w,2w+1} and B segs {2w,2w+1};
  // lane l lands at seg_base + l*16B. Lane fetches the logical quad that
  // belongs at its phys slot: A: (l&3)^(rloc&3); B: (l&3)^((rloc>>1)&3).
  const int lane  = tid & 63;
  const int wid   = tid >> 6;                      // 0..3
  const int rloc  = lane >> 2;
  const int qA4   = (((lane & 3) ^ (rloc & 3)) << 2);
  const int qB4   = (((lane & 3) ^ ((rloc >> 1) & 3)) << 2);
  const int s0    = 2 * wid, s1 = 2 * wid + 1;
  const int oS0   = s0 * 256, oS1 = s1 * 256;      // LDS float offsets
  const float* gA0 = A + (size_t)(m0 + s0 * 16 + rloc) * D_SZ + qA4;
  const float* gA1 = A + (size_t)(m0 + s1 * 16 + rloc) * D_SZ + qA4;
  const float* gB0 = W + (size_t)(n0 + s0 * 16 + rloc) * D_SZ + qB4;
  const float* gB1 = W + (size_t)(n0 + s1 * 16 + rloc) * D_SZ + qB4;

#define STAGE(BUF, KOFF)                                                      \
  do {                                                                        \
    __builtin_amdgcn_global_load_lds((gas1_t)(const void*)(gA0 + (KOFF)),     \
                                     (las3_t)(void*)(&As[BUF][oS0]), 16, 0, 0);\
    __builtin_amdgcn_global_load_lds((gas1_t)(const void*)(gA1 + (KOFF)),     \
                                     (las3_t)(void*)(&As[BUF][oS1]), 16, 0, 0);\
    __builtin_amdgcn_global_load_lds((gas1_t)(const void*)(gB0 + (KOFF)),     \
                                     (las3_t)(void*)(&Bs[BUF][oS0]), 16, 0, 0);\
    __builtin_amdgcn_global_load_lds((gas1_t)(const void*)(gB1 + (KOFF)),     \
                                     (las3_t)(void*)(&Bs[BUF][oS1]), 16, 0, 0);\
  } while (0)

  float acc[8][8];
#pragma unroll
  for (int i = 0; i < 8; ++i)
#pragma unroll
    for (int j = 0; j < 8; ++j) acc[i][j] = 0.0f;

  STAGE(0, 0);
  __syncthreads();

#pragma unroll 1
  for (int kc = 0; kc < 32; ++kc) {
    const int cur = kc & 1;
    if (kc + 1 < 32) STAGE(cur ^ 1, (kc + 1) * 16);

    const float* asb = &As[cur][0];
    const float* bsb = &Bs[cur][0];
#pragma unroll
    for (int kq = 0; kq < 4; ++kq) {
      const int bq = ((kq ^ cB) & 3) << 2;   // phys quad holding logical kq
      const int aq = ((kq ^ cA) & 3) << 2;
      float4 bfr[8];
#pragma unroll
      for (int j = 0; j < 8; ++j)
        bfr[j] = *(const float4*)&bsb[(tx + 16 * j) * 16 + bq];
#pragma unroll
      for (int i = 0; i < 8; ++i) {
        const float4 a = *(const float4*)&asb[(ty + 16 * i) * 16 + aq];
#pragma unroll
        for (int j = 0; j < 8; ++j) {
          acc[i][j] = fmaf(a.x, bfr[j].x, acc[i][j]);
          acc[i][j] = fmaf(a.y, bfr[j].y, acc[i][j]);
          acc[i][j] = fmaf(a.z, bfr[j].z, acc[i][j]);
          acc[i][j] = fmaf(a.w, bfr[j].w, acc[i][j]);
        }
      }
    }
    __syncthreads();   // drains vmcnt: next buf landed; cur reads complete.
  }
#undef STAGE

#pragma unroll
  for (int i = 0; i < 8; ++i) {
    const int m = m0 + ty + 16 * i;
#pragma unroll
    for (int j = 0; j < 8; ++j) {
      const int n = n0 + tx + 16 * j;
      Y[(size_t)m * D_SZ + n] = acc[i][j] + bias[n];
    }
  }
}

// ---------------------------------------------------------------------------
// Chunked LIF scan with warm-up (R7 flow), float2-widened: each thread owns
// TWO adjacent columns -> half the VMEM instructions (dwordx2), 2 independent
// chains per thread (2x ILP on the dependent 4-op step latency).
// T split into CHK=16 chunks of CLEN=128; 64-step warm-up per direction
// (bit-exact: 2^-64 residual + hard reset to exact 0; absmax=0 R5-R8).
// Per-column step order identical to the verified scan -> bit-exact.
// Chains rolled to unroll-4 (dependency-bound; keeps code compact per the
// R5 code-bloat lesson). Grid: BD/128 x CHK = 2048 waves (8/CU).
// ---------------------------------------------------------------------------
#define CHK  16
#define CLEN 128

__global__ __launch_bounds__(64) void scan_chunk_kernel(
    const float* __restrict__ Y,
    float* __restrict__ out)
{
#pragma clang fp contract(off)
  const int col = (blockIdx.x * 64 + threadIdx.x) * 2;  // even column
  const int c   = blockIdx.y;                           // chunk
  const int t0  = c * CLEN;
  float2 ca[32], cb[32];
  uint32_t sfx0, sfx1, sfx2, sfx3, sfy0, sfy1, sfy2, sfy3;
  uint32_t sbx0, sbx1, sbx2, sbx3, sby0, sby1, sby2, sby3;
  float vx, vy;

#define LD(R, TB)                                                             \
  _Pragma("unroll 8")                                                         \
  for (int j = 0; j < 32; ++j)                                                \
    R[j] = *(const float2*)&Y[(size_t)((TB) + j) * BD + col];

#define FCH(R, WX, WY)                                                        \
  {                                                                           \
    uint32_t wx_ = 0, wy_ = 0;                                                \
    _Pragma("unroll 4")                                                       \
    for (int j = 0; j < 32; ++j) {                                            \
      vx = vx + (R[j].x - vx) * 0.5f;                                         \
      const bool sx = (vx - 1.0f) >= 0.0f;                                    \
      wx_ |= (uint32_t)sx << j;                                               \
      vx = sx ? 0.0f : vx;                                                    \
      vy = vy + (R[j].y - vy) * 0.5f;                                         \
      const bool sy = (vy - 1.0f) >= 0.0f;                                    \
      wy_ |= (uint32_t)sy << j;                                               \
      vy = sy ? 0.0f : vy;                                                    \
    }                                                                         \
    WX = wx_; WY = wy_;                                                       \
  }

#define BCH(R, WX, WY)                                                        \
  {                                                                           \
    uint32_t wx_ = 0, wy_ = 0;                                                \
    _Pragma("unroll 4")                                                       \
    for (int j = 31; j >= 0; --j) {                                           \
      vx = vx + (R[j].x - vx) * 0.5f;                                         \
      const bool sx = (vx - 1.0f) >= 0.0f;                                    \
      wx_ |= (uint32_t)sx << j;                                               \
      vx = sx ? 0.0f : vx;                                                    \
      vy = vy + (R[j].y - vy) * 0.5f;                                         \
      const bool sy = (vy - 1.0f) >= 0.0f;                                    \
      wy_ |= (uint32_t)sy << j;                                               \
      vy = sy ? 0.0f : vy;                                                    \
    }                                                                         \
    WX = wx_; WY = wy_;                                                       \
  }

  uint32_t dx, dy;   // warm-up bit sinks (dead)

  // ---------------- forward (t ascending) ----------------
  vx = 0.0f; vy = 0.0f;
  if (c > 0) {                       // warm-up: 64 steps over tail of prev
    LD(ca, t0 - 64)
    LD(cb, t0 - 32)
    FCH(ca, dx, dy)
    LD(ca, t0)                       // real group 0 loads fly under cb chain
    FCH(cb, dx, dy)
  } else {
    LD(ca, t0)
  }
  LD(cb, t0 + 32)  FCH(ca, sfx0, sfy0)
  LD(ca, t0 + 64)  FCH(cb, sfx1, sfy1)
  LD(cb, t0 + 96)  FCH(ca, sfx2, sfy2)
                   FCH(cb, sfx3, sfy3)

  // ---------------- backward (t descending) ----------------
  vx = 0.0f; vy = 0.0f;
  if (c < CHK - 1) {                 // warm-up: 64 steps over head of next
    LD(ca, t0 + CLEN + 32)
    LD(cb, t0 + CLEN)
    BCH(ca, dx, dy)
    LD(ca, t0 + 96)                  // real group 3 loads fly under cb chain
    BCH(cb, dx, dy)
  } else {
    LD(ca, t0 + 96)
  }
  LD(cb, t0 + 64)  BCH(ca, sbx3, sby3)
  LD(ca, t0 + 32)  BCH(cb, sbx2, sby2)
  LD(cb, t0)       BCH(ca, sbx1, sby1)
                   BCH(cb, sbx0, sby0)

  // ---------------- write ----------------
#define WGRP(SFX, SFY, SBX, SBY, G)                                           \
  _Pragma("unroll 4")                                                         \
  for (int j = 0; j < 32; ++j) {                                              \
    float2 rr;                                                                \
    rr.x = (float)(((SFX >> j) & 1u) + ((SBX >> j) & 1u));                    \
    rr.y = (float)(((SFY >> j) & 1u) + ((SBY >> j) & 1u));                    \
    *(float2*)&out[(size_t)(t0 + (G) * 32 + j) * BD + col] = rr;              \
  }
  WGRP(sfx0, sfy0, sbx0, sby0, 0)
  WGRP(sfx1, sfy1, sbx1, sby1, 1)
  WGRP(sfx2, sfy2, sbx2, sby2, 2)
  WGRP(sfx3, sfy3, sbx3, sby3, 3)

#undef LD
#undef FCH
#undef BCH
#undef WGRP
}

// ---------------------------------------------------------------------------
// Fallback scans (used only if ws is too small for full Y).
// ---------------------------------------------------------------------------
__global__ __launch_bounds__(64) void lif_fwd_kernel(
    const float* __restrict__ Y, float* __restrict__ out,
    int tlen, float* __restrict__ vstate, int carry)
{
#pragma clang fp contract(off)
  const int idx = blockIdx.x * 64 + threadIdx.x;
  float v = carry ? vstate[idx] : 0.0f;
#pragma unroll 16
  for (int t = 0; t < tlen; ++t) {
    const float c = Y[(size_t)t * BD + idx];
    v = v + (c - v) * 0.5f;
    const bool s = (v - 1.0f) >= 0.0f;
    out[(size_t)t * BD + idx] = s ? 1.0f : 0.0f;
    v = s ? 0.0f : v;
  }
  vstate[idx] = v;
}

__global__ __launch_bounds__(64) void lif_bwd_kernel(
    const float* __restrict__ Y, float* __restrict__ out,
    int tlen, float* __restrict__ vstate, int carry)
{
#pragma clang fp contract(off)
  const int idx = blockIdx.x * 64 + threadIdx.x;
  float v = carry ? vstate[idx] : 0.0f;
#pragma unroll 16
  for (int tt = 0; tt < tlen; ++tt) {
    const size_t t = (size_t)(tlen - 1 - tt);
    const float c = Y[t * BD + idx];
    v = v + (c - v) * 0.5f;
    const bool s = (v - 1.0f) >= 0.0f;
    out[t * BD + idx] += s ? 1.0f : 0.0f;
    v = s ? 0.0f : v;
  }
  vstate[idx] = v;
}

// ---------------------------------------------------------------------------
extern "C" void kernel_launch(void* const* d_in, const int* in_sizes, int n_in,
                              void* d_out, int out_size, void* d_ws, size_t ws_size,
                              hipStream_t stream)
{
  const float* x = (const float*)d_in[0];   // [T, B, D]
  const float* W = (const float*)d_in[1];   // [D, D]
  const float* b = (const float*)d_in[2];   // [D]
  float* out = (float*)d_out;               // [T, B, D]

  const size_t full_bytes = (size_t)T_LEN * BD * sizeof(float);     // 134 MB
  const size_t vbytes     = (size_t)BD * sizeof(float);

  if (ws_size >= full_bytes) {
    float* Y = (float*)d_ws;
    dim3 grid(T_LEN * B_SZ / BM, D_SZ / BN);
    gemm8x8_kernel<<<grid, 256, 0, stream>>>(x, W, b, Y);
    scan_chunk_kernel<<<dim3(BD / 128, CHK), 64, 0, stream>>>(Y, out);
  } else {
    // Chunked fallback; Tc a power-of-two divisor of T_LEN (>=4) so chunk
    // rows are a multiple of BM=128.
    const size_t avail = ws_size > vbytes ? ws_size - vbytes : 0;
    int Tc = T_LEN;
    while (Tc > 4 && (size_t)Tc * BD * sizeof(float) > avail) Tc >>= 1;
    float* Y      = (float*)d_ws;
    float* vstate = (float*)((char*)d_ws + (size_t)Tc * BD * sizeof(float));

    int first = 1;
    for (int t0 = 0; t0 < T_LEN; t0 += Tc) {
      dim3 grid(Tc * B_SZ / BM, D_SZ / BN);
      gemm8x8_kernel<<<grid, 256, 0, stream>>>(x + (size_t)t0 * BD, W, b, Y);
      lif_fwd_kernel<<<BD / 64, 64, 0, stream>>>(Y, out + (size_t)t0 * BD, Tc,
                                                 vstate, first ? 0 : 1);
      first = 0;
    }
    first = 1;
    for (int t0 = T_LEN - Tc; t0 >= 0; t0 -= Tc) {
      dim3 grid(Tc * B_SZ / BM, D_SZ / BN);
      gemm8x8_kernel<<<grid, 256, 0, stream>>>(x + (size_t)t0 * BD, W, b, Y);
      lif_bwd_kernel<<<BD / 64, 64, 0, stream>>>(Y, out + (size_t)t0 * BD, Tc,
                                                 vstate, first ? 0 : 1);
      first = 0;
    }
  }
}

// Round 10
// 650.717 us; speedup vs baseline: 1.2248x; 1.2248x over previous
//
#include <hip/hip_runtime.h>
#include <cstddef>
#include <cstdint>

// Shapes fixed by reference setup_inputs():
#define T_LEN 2048
#define B_SZ  32
#define D_SZ  512
#define BD    (B_SZ * D_SZ)   // 16384

// ---------------------------------------------------------------------------
// GEMM — EXACT R5/R6/R9 kernel (best measured: 464-484 us, VGPR 80,
// VALUBusy 83-84%, occupancy 30%; reproduced three times). Variants that
// LOST to this body: R2 reg-dbuf (733), R3 full-swizzle (752), R4 hybrid
// ds_write (543), R7 named-A read-once (516), R8 3-buf counted-vmcnt (500).
// Do not restructure without disasm-level evidence.
// Per output element: single sequential fmaf chain over k=0..511 ascending
// (k0 asc, kq asc, x/y/z/w asc), then + bias[e]. Bit-exact vs ref.
//  - A and B staged via global_load_lds into linear [2][128*16] tiles (32 KB).
//  - XOR quad swizzles, inverse-swizzled global source (rule #21):
//    A: p=q^(row&3); B: p=q^((row>>1)&3). Read offsets loop-invariant.
//  - ONE __syncthreads per 16-wide K-chunk; next chunk's glds issued before
//    compute, drained by the barrier.
//  - Bijective XCD swizzle (FETCH 272->85 MB proven).
// NOTE: SQ_LDS_BANK_CONFLICT ~3.3e7 is a glds wide-write artifact.
// NOTE: plain __launch_bounds__(256); (256,4) spilled acc (8.5x). Keep.
// ---------------------------------------------------------------------------
#define BM   128
#define BN   128

typedef const __attribute__((address_space(1))) uint32_t* gas1_t;
typedef __attribute__((address_space(3))) uint32_t* las3_t;

__global__ __launch_bounds__(256) void gemm8x8_kernel(
    const float* __restrict__ A,     // [rows, 512]
    const float* __restrict__ W,     // [512, 512]
    const float* __restrict__ bias,  // [512]
    float* __restrict__ Y)           // [rows, 512]
{
#pragma clang fp contract(off)
  __shared__ float As[2][BM * 16];     // 8 KB per buf, linear, glds dest
  __shared__ float Bs[2][BN * 16];     // 8 KB per buf, linear, glds dest

  const int tid = threadIdx.x;
  const int tx  = tid & 15;          // n-lane: n = tx + 16*j
  const int ty  = tid >> 4;          // m-lane: m = ty + 16*i (0..15)
  const int cA  = ty & 3;            // A read-side quad XOR
  const int cB  = (tx >> 1) & 3;     // B read-side quad XOR

  // Bijective XCD swizzle (n-fast).
  const int nwg  = (int)(gridDim.x * gridDim.y);
  const int orig = (int)(blockIdx.y * gridDim.x + blockIdx.x);
  const int q    = nwg >> 3, r = nwg & 7;
  const int xcd  = orig & 7, loc = orig >> 3;
  const int tix  = (xcd < r ? xcd * (q + 1) : r * (q + 1) + (xcd - r) * q) + loc;
  const int m0   = (tix >> 2) * BM;   // gridDim.y == 4 (D_SZ/BN)
  const int n0   = (tix & 3) * BN;

  // glds staging: wave w stages A segs {2w,2w+1} and B segs {2w,2w+1};
  // lane l lands at seg_base + l*16B. Lane fetches the logical quad that
  // belongs at its phys slot: A: (l&3)^(rloc&3); B: (l&3)^((rloc>>1)&3).
  const int lane  = tid & 63;
  const int wid   = tid >> 6;                      // 0..3
  const int rloc  = lane >> 2;
  const int qA4   = (((lane & 3) ^ (rloc & 3)) << 2);
  const int qB4   = (((lane & 3) ^ ((rloc >> 1) & 3)) << 2);
  const int s0    = 2 * wid, s1 = 2 * wid + 1;
  const int oS0   = s0 * 256, oS1 = s1 * 256;      // LDS float offsets
  const float* gA0 = A + (size_t)(m0 + s0 * 16 + rloc) * D_SZ + qA4;
  const float* gA1 = A + (size_t)(m0 + s1 * 16 + rloc) * D_SZ + qA4;
  const float* gB0 = W + (size_t)(n0 + s0 * 16 + rloc) * D_SZ + qB4;
  const float* gB1 = W + (size_t)(n0 + s1 * 16 + rloc) * D_SZ + qB4;

#define STAGE(BUF, KOFF)                                                      \
  do {                                                                        \
    __builtin_amdgcn_global_load_lds((gas1_t)(const void*)(gA0 + (KOFF)),     \
                                     (las3_t)(void*)(&As[BUF][oS0]), 16, 0, 0);\
    __builtin_amdgcn_global_load_lds((gas1_t)(const void*)(gA1 + (KOFF)),     \
                                     (las3_t)(void*)(&As[BUF][oS1]), 16, 0, 0);\
    __builtin_amdgcn_global_load_lds((gas1_t)(const void*)(gB0 + (KOFF)),     \
                                     (las3_t)(void*)(&Bs[BUF][oS0]), 16, 0, 0);\
    __builtin_amdgcn_global_load_lds((gas1_t)(const void*)(gB1 + (KOFF)),     \
                                     (las3_t)(void*)(&Bs[BUF][oS1]), 16, 0, 0);\
  } while (0)

  float acc[8][8];
#pragma unroll
  for (int i = 0; i < 8; ++i)
#pragma unroll
    for (int j = 0; j < 8; ++j) acc[i][j] = 0.0f;

  STAGE(0, 0);
  __syncthreads();

#pragma unroll 1
  for (int kc = 0; kc < 32; ++kc) {
    const int cur = kc & 1;
    if (kc + 1 < 32) STAGE(cur ^ 1, (kc + 1) * 16);

    const float* asb = &As[cur][0];
    const float* bsb = &Bs[cur][0];
#pragma unroll
    for (int kq = 0; kq < 4; ++kq) {
      const int bq = ((kq ^ cB) & 3) << 2;   // phys quad holding logical kq
      const int aq = ((kq ^ cA) & 3) << 2;
      float4 bfr[8];
#pragma unroll
      for (int j = 0; j < 8; ++j)
        bfr[j] = *(const float4*)&bsb[(tx + 16 * j) * 16 + bq];
#pragma unroll
      for (int i = 0; i < 8; ++i) {
        const float4 a = *(const float4*)&asb[(ty + 16 * i) * 16 + aq];
#pragma unroll
        for (int j = 0; j < 8; ++j) {
          acc[i][j] = fmaf(a.x, bfr[j].x, acc[i][j]);
          acc[i][j] = fmaf(a.y, bfr[j].y, acc[i][j]);
          acc[i][j] = fmaf(a.z, bfr[j].z, acc[i][j]);
          acc[i][j] = fmaf(a.w, bfr[j].w, acc[i][j]);
        }
      }
    }
    __syncthreads();   // drains vmcnt: next buf landed; cur reads complete.
  }
#undef STAGE

#pragma unroll
  for (int i = 0; i < 8; ++i) {
    const int m = m0 + ty + 16 * i;
#pragma unroll
    for (int j = 0; j < 8; ++j) {
      const int n = n0 + tx + 16 * j;
      Y[(size_t)m * D_SZ + n] = acc[i][j] + bias[n];
    }
  }
}

// ---------------------------------------------------------------------------
// Chunked LIF scan — EXACT R7 kernel (best measured: ~160 us). One column
// per thread (scalar loads), ca/cb ping-pong so each group's 32 loads issue
// under the previous group's dependent chain. 4096 waves (16/CU).
// Variants that LOST: R4 shared-creg serial (170), R5 CLEN=256 mega-unroll
// (297), R9 float2 two-column (319, buffer spill to scratch).
// T split into CHK=16 chunks of CLEN=128; 64-step warm-up per direction
// (bit-exact: 2^-64 residual + hard reset to exact 0; absmax=0 R5-R9).
// ---------------------------------------------------------------------------
#define CHK  16
#define CLEN 128

__global__ __launch_bounds__(64) void scan_chunk_kernel(
    const float* __restrict__ Y,
    float* __restrict__ out)
{
#pragma clang fp contract(off)
  const int idx = blockIdx.x * 64 + threadIdx.x;   // column in [0, BD)
  const int c   = blockIdx.y;                      // chunk
  const int t0  = c * CLEN;
  float ca[32], cb[32];
  uint32_t sf0, sf1, sf2, sf3, sb0, sb1, sb2, sb3;
  float v;

#define LD(R, TB)                                                             \
  _Pragma("unroll")                                                           \
  for (int j = 0; j < 32; ++j) R[j] = Y[(size_t)((TB) + j) * BD + idx];

#define FCH(R, W)                                                             \
  {                                                                           \
    uint32_t w_ = 0;                                                          \
    _Pragma("unroll")                                                         \
    for (int j = 0; j < 32; ++j) {                                            \
      v = v + (R[j] - v) * 0.5f;                                              \
      const bool s = (v - 1.0f) >= 0.0f;                                      \
      w_ |= (uint32_t)s << j;                                                 \
      v = s ? 0.0f : v;                                                       \
    }                                                                         \
    W = w_;                                                                   \
  }

#define BCH(R, W)                                                             \
  {                                                                           \
    uint32_t w_ = 0;                                                          \
    _Pragma("unroll")                                                         \
    for (int j = 31; j >= 0; --j) {                                           \
      v = v + (R[j] - v) * 0.5f;                                              \
      const bool s = (v - 1.0f) >= 0.0f;                                      \
      w_ |= (uint32_t)s << j;                                                 \
      v = s ? 0.0f : v;                                                       \
    }                                                                         \
    W = w_;                                                                   \
  }

  uint32_t wdump;   // warm-up bit sink (dead)

  // ---------------- forward (t ascending) ----------------
  v = 0.0f;
  if (c > 0) {                       // warm-up: 64 steps over tail of prev
    LD(ca, t0 - 64)
    LD(cb, t0 - 32)
    FCH(ca, wdump)
    LD(ca, t0)                       // real group 0 loads fly under cb chain
    FCH(cb, wdump)
  } else {
    LD(ca, t0)
  }
  LD(cb, t0 + 32)  FCH(ca, sf0)
  LD(ca, t0 + 64)  FCH(cb, sf1)
  LD(cb, t0 + 96)  FCH(ca, sf2)
                   FCH(cb, sf3)

  // ---------------- backward (t descending) ----------------
  v = 0.0f;
  if (c < CHK - 1) {                 // warm-up: 64 steps over head of next
    LD(ca, t0 + CLEN + 32)
    LD(cb, t0 + CLEN)
    BCH(ca, wdump)
    LD(ca, t0 + 96)                  // real group 3 loads fly under cb chain
    BCH(cb, wdump)
  } else {
    LD(ca, t0 + 96)
  }
  LD(cb, t0 + 64)  BCH(ca, sb3)
  LD(ca, t0 + 32)  BCH(cb, sb2)
  LD(cb, t0)       BCH(ca, sb1)
                   BCH(cb, sb0)

  // ---------------- write ----------------
#define WGRP(SF, SB, G)                                                       \
  _Pragma("unroll")                                                           \
  for (int j = 0; j < 32; ++j)                                                \
    out[(size_t)(t0 + (G) * 32 + j) * BD + idx] =                             \
        (float)(((SF >> j) & 1u) + ((SB >> j) & 1u));
  WGRP(sf0, sb0, 0) WGRP(sf1, sb1, 1) WGRP(sf2, sb2, 2) WGRP(sf3, sb3, 3)

#undef LD
#undef FCH
#undef BCH
#undef WGRP
}

// ---------------------------------------------------------------------------
// Fallback scans (used only if ws is too small for full Y).
// ---------------------------------------------------------------------------
__global__ __launch_bounds__(64) void lif_fwd_kernel(
    const float* __restrict__ Y, float* __restrict__ out,
    int tlen, float* __restrict__ vstate, int carry)
{
#pragma clang fp contract(off)
  const int idx = blockIdx.x * 64 + threadIdx.x;
  float v = carry ? vstate[idx] : 0.0f;
#pragma unroll 16
  for (int t = 0; t < tlen; ++t) {
    const float c = Y[(size_t)t * BD + idx];
    v = v + (c - v) * 0.5f;
    const bool s = (v - 1.0f) >= 0.0f;
    out[(size_t)t * BD + idx] = s ? 1.0f : 0.0f;
    v = s ? 0.0f : v;
  }
  vstate[idx] = v;
}

__global__ __launch_bounds__(64) void lif_bwd_kernel(
    const float* __restrict__ Y, float* __restrict__ out,
    int tlen, float* __restrict__ vstate, int carry)
{
#pragma clang fp contract(off)
  const int idx = blockIdx.x * 64 + threadIdx.x;
  float v = carry ? vstate[idx] : 0.0f;
#pragma unroll 16
  for (int tt = 0; tt < tlen; ++tt) {
    const size_t t = (size_t)(tlen - 1 - tt);
    const float c = Y[t * BD + idx];
    v = v + (c - v) * 0.5f;
    const bool s = (v - 1.0f) >= 0.0f;
    out[t * BD + idx] += s ? 1.0f : 0.0f;
    v = s ? 0.0f : v;
  }
  vstate[idx] = v;
}

// ---------------------------------------------------------------------------
extern "C" void kernel_launch(void* const* d_in, const int* in_sizes, int n_in,
                              void* d_out, int out_size, void* d_ws, size_t ws_size,
                              hipStream_t stream)
{
  const float* x = (const float*)d_in[0];   // [T, B, D]
  const float* W = (const float*)d_in[1];   // [D, D]
  const float* b = (const float*)d_in[2];   // [D]
  float* out = (float*)d_out;               // [T, B, D]

  const size_t full_bytes = (size_t)T_LEN * BD * sizeof(float);     // 134 MB
  const size_t vbytes     = (size_t)BD * sizeof(float);

  if (ws_size >= full_bytes) {
    float* Y = (float*)d_ws;
    dim3 grid(T_LEN * B_SZ / BM, D_SZ / BN);
    gemm8x8_kernel<<<grid, 256, 0, stream>>>(x, W, b, Y);
    scan_chunk_kernel<<<dim3(BD / 64, CHK), 64, 0, stream>>>(Y, out);
  } else {
    // Chunked fallback; Tc a power-of-two divisor of T_LEN (>=4) so chunk
    // rows are a multiple of BM=128.
    const size_t avail = ws_size > vbytes ? ws_size - vbytes : 0;
    int Tc = T_LEN;
    while (Tc > 4 && (size_t)Tc * BD * sizeof(float) > avail) Tc >>= 1;
    float* Y      = (float*)d_ws;
    float* vstate = (float*)((char*)d_ws + (size_t)Tc * BD * sizeof(float));

    int first = 1;
    for (int t0 = 0; t0 < T_LEN; t0 += Tc) {
      dim3 grid(Tc * B_SZ / BM, D_SZ / BN);
      gemm8x8_kernel<<<grid, 256, 0, stream>>>(x + (size_t)t0 * BD, W, b, Y);
      lif_fwd_kernel<<<BD / 64, 64, 0, stream>>>(Y, out + (size_t)t0 * BD, Tc,
                                                 vstate, first ? 0 : 1);
      first = 0;
    }
    first = 1;
    for (int t0 = T_LEN - Tc; t0 >= 0; t0 -= Tc) {
      dim3 grid(Tc * B_SZ / BM, D_SZ / BN);
      gemm8x8_kernel<<<grid, 256, 0, stream>>>(x + (size_t)t0 * BD, W, b, Y);
      lif_bwd_kernel<<<BD / 64, 64, 0, stream>>>(Y, out + (size_t)t0 * BD, Tc,
                                                 vstate, first ? 0 : 1);
      first = 0;
    }
  }
}